// Round 6
// baseline (166.557 us; speedup 1.0000x reference)
//
#include <hip/hip_runtime.h>

// GCNII layer: N=100000 nodes, C=128, E=640000 edges, fp32.
//   hidden = (1-ALPHA) * segment_sum(attr * x[col], row) + ALPHA * init_x
//   out    = BETA * (hidden @ W) + (1-BETA) * hidden
//          = hidden @ (BETA*W + (1-BETA)*I)          <- blend folded into W
//
// Pipeline: prep (x->bf16 + zero cnt + folded/transposed Wt) -> hist ->
// blockreduce -> blockscan -> build packed CSR -> FUSED gather+MFMA-GEMM
// (gather 64 rows into swizzled LDS bf16 tile, then MFMA vs Wt, write out).
// Workspace: cnt[N_pad] | partials[256] | recs[E f2] | Wt[128*128 bf16] | xb[N*128 bf16].

#define ALPHA 0.1f
#define BETA  0.5f
#define C_DIM 128

typedef __attribute__((ext_vector_type(8))) short short8v;   // 8 bf16 (4 VGPR)
typedef __attribute__((ext_vector_type(4))) float f32x4;

__device__ inline unsigned bf16rn(float f) {            // RTNE fp32->bf16 bits
    unsigned u = __float_as_uint(f);
    return (u + 0x7FFFu + ((u >> 16) & 1u)) >> 16;
}
__device__ inline unsigned pack2(float lo, float hi) {
    return bf16rn(lo) | (bf16rn(hi) << 16);
}

// K0: convert x -> bf16 (8 elems/thread), zero cnt[N], build folded Wt.
// Wt[n][k] = bf16( BETA*W[k][n] + (k==n)*(1-BETA) )
__global__ void k_prep(const float4* __restrict__ x4, uint4* __restrict__ xb,
                       int n8, int* __restrict__ cnt, int N,
                       const float* __restrict__ W, ushort* __restrict__ Wt) {
    int i = blockIdx.x * 256 + threadIdx.x;
    if (i < n8) {
        float4 a = x4[2 * i], b = x4[2 * i + 1];
        uint4 o;
        o.x = pack2(a.x, a.y); o.y = pack2(a.z, a.w);
        o.z = pack2(b.x, b.y); o.w = pack2(b.z, b.w);
        xb[i] = o;
    }
    if (i < N) cnt[i] = 0;
    if (i < C_DIM * C_DIM) {
        int n = i >> 7, k = i & 127;
        float v = BETA * W[k * C_DIM + n] + ((k == n) ? (1.0f - BETA) : 0.0f);
        Wt[i] = (ushort)bf16rn(v);
    }
}

__global__ void k_hist(const int* __restrict__ ei, int* __restrict__ cnt, int E) {
    int e = blockIdx.x * 256 + threadIdx.x;
    if (e < E) atomicAdd(&cnt[ei[e]], 1);
}

// partials[b] = sum of cnt[b*1024 .. b*1024+1024)
__global__ void k_blockreduce(const int* __restrict__ cnt, int* __restrict__ partials, int n) {
    __shared__ int lds[256];
    int t = threadIdx.x;
    int base = blockIdx.x * 1024;
    int s = 0;
#pragma unroll
    for (int j = 0; j < 4; ++j) {
        int idx = base + j * 256 + t;
        if (idx < n) s += cnt[idx];
    }
    lds[t] = s;
    __syncthreads();
    for (int d = 128; d > 0; d >>= 1) {
        if (t < d) lds[t] += lds[t + d];
        __syncthreads();
    }
    if (t == 0) partials[blockIdx.x] = lds[0];
}

// block b: exclusive scan of cnt[b*1024 ..] in place; base = sum(partials[<b])
// (requires gridDim.x <= 256)
__global__ void k_blockscan(int* __restrict__ cnt, const int* __restrict__ partials, int n) {
    __shared__ int lds[256];
    __shared__ int base_s;
    int t = threadIdx.x;

    int pv = (t < blockIdx.x) ? partials[t] : 0;
    lds[t] = pv;
    __syncthreads();
    for (int d = 128; d > 0; d >>= 1) {
        if (t < d) lds[t] += lds[t + d];
        __syncthreads();
    }
    if (t == 0) base_s = lds[0];
    __syncthreads();

    int base = blockIdx.x * 1024 + t * 4;
    int4 v = {0, 0, 0, 0};
    if (base + 3 < n) v = *(const int4*)(cnt + base);
    else {
        if (base + 0 < n) v.x = cnt[base + 0];
        if (base + 1 < n) v.y = cnt[base + 1];
        if (base + 2 < n) v.z = cnt[base + 2];
        if (base + 3 < n) v.w = cnt[base + 3];
    }
    int s = v.x + v.y + v.z + v.w;
    lds[t] = s;
    for (int d = 1; d < 256; d <<= 1) {
        __syncthreads();
        int tmp = (t >= d) ? lds[t - d] : 0;
        __syncthreads();
        lds[t] += tmp;
    }
    __syncthreads();
    int thrBase = base_s + lds[t] - s;
    int4 o;
    o.x = thrBase;
    o.y = thrBase + v.x;
    o.z = thrBase + v.x + v.y;
    o.w = thrBase + v.x + v.y + v.z;
    if (base + 3 < n) *(int4*)(cnt + base) = o;
    else {
        if (base + 0 < n) cnt[base + 0] = o.x;
        if (base + 1 < n) cnt[base + 1] = o.y;
        if (base + 2 < n) cnt[base + 2] = o.z;
        if (base + 3 < n) cnt[base + 3] = o.w;
    }
}

// bin edges into CSR order as packed 8B records (col, attr*(1-ALPHA))
__global__ void k_build(const int* __restrict__ ei, const float* __restrict__ attr,
                        int* __restrict__ cur, float2* __restrict__ recs, int E) {
    int e = blockIdx.x * 256 + threadIdx.x;
    if (e >= E) return;
    int row = ei[e];
    int pos = atomicAdd(&cur[row], 1);
    recs[pos] = make_float2(__int_as_float(ei[E + e]), (1.0f - ALPHA) * attr[e]);
}

__device__ inline void bf16_fma4(float4& acc, float a, uint2 v) {
    acc.x += a * __uint_as_float(v.x << 16);
    acc.y += a * __uint_as_float(v.x & 0xffff0000u);
    acc.z += a * __uint_as_float(v.y << 16);
    acc.w += a * __uint_as_float(v.y & 0xffff0000u);
}

// FUSED: gather 64 rows into swizzled bf16 LDS tile, then MFMA GEMM vs Wt.
// Gather: 8 half-wave slots x 8 rows; 32 lanes/row, 4 channels/lane, 4-way
// edge unroll. LDS swizzle: word_in_row ^= (row&7)<<2 (word=4B) -> both the
// uint2 writes and the stride-256B ds_read_b128 A-reads are ~conflict-free.
// GEMM: 4 waves x 16 rows; B frags from 32KB L1-resident Wt; out fp32 once.
template <int USE_BF16>
__global__ __launch_bounds__(256, 6)
void k_fused(const void* __restrict__ xsrc, const int* __restrict__ cnt,
             const float2* __restrict__ recs, const float4* __restrict__ init4,
             const ushort* __restrict__ Wt, float* __restrict__ out, int N) {
    __shared__ ushort hs[64 * C_DIM];          // 16 KB swizzled bf16 tile
    const int tid = threadIdx.x;
    const long R0 = (long)blockIdx.x * 64;

    // ---------------- gather phase ----------------
    {
        const int slot = tid >> 5;             // 0..7
        const int c4 = tid & 31;
        for (int i = 0; i < 8; ++i) {
            int rl = i * 8 + slot;             // local row 0..63
            long r = R0 + rl;
            float4 acc = {0.f, 0.f, 0.f, 0.f};
            if (r < N) {
                int start = (r == 0) ? 0 : cnt[r - 1];
                int end = cnt[r];
                int k = start;
                if (USE_BF16) {
                    const uint2* xb2 = (const uint2*)xsrc;
                    for (; k + 4 <= end; k += 4) {
                        float2 r0 = recs[k + 0];
                        float2 r1 = recs[k + 1];
                        float2 r2 = recs[k + 2];
                        float2 r3 = recs[k + 3];
                        uint2 v0 = xb2[(size_t)__float_as_int(r0.x) * 32 + c4];
                        uint2 v1 = xb2[(size_t)__float_as_int(r1.x) * 32 + c4];
                        uint2 v2 = xb2[(size_t)__float_as_int(r2.x) * 32 + c4];
                        uint2 v3 = xb2[(size_t)__float_as_int(r3.x) * 32 + c4];
                        bf16_fma4(acc, r0.y, v0);
                        bf16_fma4(acc, r1.y, v1);
                        bf16_fma4(acc, r2.y, v2);
                        bf16_fma4(acc, r3.y, v3);
                    }
                    if (k + 2 <= end) {
                        float2 r0 = recs[k + 0];
                        float2 r1 = recs[k + 1];
                        uint2 v0 = xb2[(size_t)__float_as_int(r0.x) * 32 + c4];
                        uint2 v1 = xb2[(size_t)__float_as_int(r1.x) * 32 + c4];
                        bf16_fma4(acc, r0.y, v0);
                        bf16_fma4(acc, r1.y, v1);
                        k += 2;
                    }
                    if (k < end) {
                        float2 r0 = recs[k];
                        uint2 v0 = xb2[(size_t)__float_as_int(r0.x) * 32 + c4];
                        bf16_fma4(acc, r0.y, v0);
                    }
                } else {
                    const float4* x4 = (const float4*)xsrc;
                    for (; k < end; ++k) {
                        float2 rec = recs[k];
                        float4 xv = x4[(size_t)__float_as_int(rec.x) * 32 + c4];
                        float a = rec.y;
                        acc.x += a * xv.x; acc.y += a * xv.y;
                        acc.z += a * xv.z; acc.w += a * xv.w;
                    }
                }
                float4 iv = init4[r * 32 + c4];
                acc.x += ALPHA * iv.x; acc.y += ALPHA * iv.y;
                acc.z += ALPHA * iv.z; acc.w += ALPHA * iv.w;
            }
            uint2 o;
            o.x = pack2(acc.x, acc.y);
            o.y = pack2(acc.z, acc.w);
            int word = rl * 64 + ((c4 * 2) ^ ((rl & 7) << 2));
            *(uint2*)&hs[word * 2] = o;
        }
    }
    __syncthreads();

    // ---------------- GEMM phase ----------------
    {
        const int lane = tid & 63;
        const int wv = tid >> 6;               // 0..3, owns 16 rows
        const int m = lane & 15, g = lane >> 4;
        const uint4* W16 = (const uint4*)Wt;   // Wt[n][k]: 16 uint4 per row

        f32x4 acc[8];
#pragma unroll
        for (int nt = 0; nt < 8; ++nt) acc[nt] = (f32x4){0.f, 0.f, 0.f, 0.f};

        const int rl = wv * 16 + m;            // A row for this lane
#pragma unroll
        for (int ks = 0; ks < 4; ++ks) {
            int word = rl * 64 + ((ks * 16 + g * 4) ^ ((rl & 7) << 2));
            short8v a = *(const short8v*)&hs[word * 2];
#pragma unroll
            for (int nt = 0; nt < 8; ++nt) {
                union { uint4 q; short8v v; } b;
                b.q = W16[(nt * 16 + m) * 16 + (ks * 4 + g)];
                acc[nt] = __builtin_amdgcn_mfma_f32_16x16x32_bf16(a, b.v, acc[nt], 0, 0, 0);
            }
        }

        // C/D layout: col = lane&15 (=m as n-index), row = g*4 + reg
        long rbase = R0 + wv * 16 + g * 4;
#pragma unroll
        for (int reg = 0; reg < 4; ++reg) {
            long r = rbase + reg;
            if (r >= N) continue;
            float* outp = out + r * C_DIM + m;
#pragma unroll
            for (int nt = 0; nt < 8; ++nt) outp[nt * 16] = acc[nt][reg];
        }
    }
}

extern "C" void kernel_launch(void* const* d_in, const int* in_sizes, int n_in,
                              void* d_out, int out_size, void* d_ws, size_t ws_size,
                              hipStream_t stream) {
    const float* x      = (const float*)d_in[0];
    const int*   ei     = (const int*)d_in[1];
    const float* attr   = (const float*)d_in[2];
    const float* init_x = (const float*)d_in[3];
    const float* W      = (const float*)d_in[4];
    float* out = (float*)d_out;

    const int N = in_sizes[0] / C_DIM;
    const int E = in_sizes[2];

    const int N_pad = (N + 255) & ~255;
    const size_t cnt_bytes = (size_t)N_pad * 4;
    const size_t rec_bytes = (size_t)E * 8;
    const size_t wt_bytes  = (size_t)C_DIM * C_DIM * 2;   // 32 KB
    const size_t xb_bytes  = (size_t)N * C_DIM * 2;       // bf16 copy of x
    const size_t base_need = cnt_bytes + 1024 + rec_bytes + wt_bytes;
    const bool use_bf16 = ws_size >= base_need + xb_bytes;

    char* wsp = (char*)d_ws;
    int*    cnt      = (int*)wsp;
    int*    partials = cnt + N_pad;
    float2* recs     = (float2*)((char*)partials + 1024);
    ushort* Wt       = (ushort*)((char*)recs + rec_bytes);
    uint4*  xb       = use_bf16 ? (uint4*)((char*)Wt + wt_bytes) : nullptr;

    const int B = (N + 1023) / 1024;   // scan blocks (98 for N=100000), must be <=256
    const int n8 = use_bf16 ? (N * C_DIM / 8) : 0;
    int prep_elems = (n8 > N) ? n8 : N;
    if (prep_elems < C_DIM * C_DIM) prep_elems = C_DIM * C_DIM;

    k_prep<<<(prep_elems + 255) / 256, 256, 0, stream>>>((const float4*)x, xb, n8,
                                                         cnt, N, W, Wt);
    k_hist<<<(E + 255) / 256, 256, 0, stream>>>(ei, cnt, E);
    k_blockreduce<<<B, 256, 0, stream>>>(cnt, partials, N);
    k_blockscan<<<B, 256, 0, stream>>>(cnt, partials, N);
    k_build<<<(E + 255) / 256, 256, 0, stream>>>(ei, attr, cnt, recs, E);
    if (use_bf16) {
        k_fused<1><<<(N + 63) / 64, 256, 0, stream>>>((const void*)xb, cnt, recs,
                                                      (const float4*)init_x, Wt, out, N);
    } else {
        k_fused<0><<<(N + 63) / 64, 256, 0, stream>>>((const void*)x, cnt, recs,
                                                      (const float4*)init_x, Wt, out, N);
    }
}

// Round 7
// 139.160 us; speedup vs baseline: 1.1969x; 1.1969x over previous
//
#include <hip/hip_runtime.h>

// GCNII layer: N=100000 nodes, C=128, E=640000 edges, fp32.
//   hidden = (1-ALPHA) * segment_sum(attr * x[col], row) + ALPHA * init_x
//   out    = BETA * (hidden @ W) + (1-BETA) * hidden
//          = hidden @ (BETA*W + (1-BETA)*I)          <- blend folded into W
//
// Pipeline: prep (x->bf16 + zero cnt + folded/transposed Wt) -> hist ->
// blockreduce -> blockscan -> build packed CSR -> FUSED gather+MFMA-GEMM.
// Fused tile = 16 rows/block, ONE row per 16-lane group (no sequential rows
// -> full gather MLP), 4KB swizzled LDS bf16 tile, 8 MFMA/wave vs Wt.
// Workspace: cnt[N_pad] | partials[256] | recs[E f2] | Wt[128*128 bf16] | xb[N*128 bf16].

#define ALPHA 0.1f
#define BETA  0.5f
#define C_DIM 128

typedef __attribute__((ext_vector_type(8))) short short8v;   // 8 bf16 (4 VGPR)
typedef __attribute__((ext_vector_type(4))) float f32x4;

__device__ inline unsigned bf16rn(float f) {            // RTNE fp32->bf16 bits
    unsigned u = __float_as_uint(f);
    return (u + 0x7FFFu + ((u >> 16) & 1u)) >> 16;
}
__device__ inline unsigned pack2(float lo, float hi) {
    return bf16rn(lo) | (bf16rn(hi) << 16);
}

// K0: convert x -> bf16 (8 elems/thread), zero cnt[N], build folded Wt.
// Wt[n][k] = bf16( BETA*W[k][n] + (k==n)*(1-BETA) )
__global__ void k_prep(const float4* __restrict__ x4, uint4* __restrict__ xb,
                       int n8, int* __restrict__ cnt, int N,
                       const float* __restrict__ W, ushort* __restrict__ Wt) {
    int i = blockIdx.x * 256 + threadIdx.x;
    if (i < n8) {
        float4 a = x4[2 * i], b = x4[2 * i + 1];
        uint4 o;
        o.x = pack2(a.x, a.y); o.y = pack2(a.z, a.w);
        o.z = pack2(b.x, b.y); o.w = pack2(b.z, b.w);
        xb[i] = o;
    }
    if (i < N) cnt[i] = 0;
    if (i < C_DIM * C_DIM) {
        int n = i >> 7, k = i & 127;
        float v = BETA * W[k * C_DIM + n] + ((k == n) ? (1.0f - BETA) : 0.0f);
        Wt[i] = (ushort)bf16rn(v);
    }
}

__global__ void k_hist(const int* __restrict__ ei, int* __restrict__ cnt, int E) {
    int e = blockIdx.x * 256 + threadIdx.x;
    if (e < E) atomicAdd(&cnt[ei[e]], 1);
}

// partials[b] = sum of cnt[b*1024 .. b*1024+1024)
__global__ void k_blockreduce(const int* __restrict__ cnt, int* __restrict__ partials, int n) {
    __shared__ int lds[256];
    int t = threadIdx.x;
    int base = blockIdx.x * 1024;
    int s = 0;
#pragma unroll
    for (int j = 0; j < 4; ++j) {
        int idx = base + j * 256 + t;
        if (idx < n) s += cnt[idx];
    }
    lds[t] = s;
    __syncthreads();
    for (int d = 128; d > 0; d >>= 1) {
        if (t < d) lds[t] += lds[t + d];
        __syncthreads();
    }
    if (t == 0) partials[blockIdx.x] = lds[0];
}

// block b: exclusive scan of cnt[b*1024 ..] in place; base = sum(partials[<b])
// (requires gridDim.x <= 256)
__global__ void k_blockscan(int* __restrict__ cnt, const int* __restrict__ partials, int n) {
    __shared__ int lds[256];
    __shared__ int base_s;
    int t = threadIdx.x;

    int pv = (t < blockIdx.x) ? partials[t] : 0;
    lds[t] = pv;
    __syncthreads();
    for (int d = 128; d > 0; d >>= 1) {
        if (t < d) lds[t] += lds[t + d];
        __syncthreads();
    }
    if (t == 0) base_s = lds[0];
    __syncthreads();

    int base = blockIdx.x * 1024 + t * 4;
    int4 v = {0, 0, 0, 0};
    if (base + 3 < n) v = *(const int4*)(cnt + base);
    else {
        if (base + 0 < n) v.x = cnt[base + 0];
        if (base + 1 < n) v.y = cnt[base + 1];
        if (base + 2 < n) v.z = cnt[base + 2];
        if (base + 3 < n) v.w = cnt[base + 3];
    }
    int s = v.x + v.y + v.z + v.w;
    lds[t] = s;
    for (int d = 1; d < 256; d <<= 1) {
        __syncthreads();
        int tmp = (t >= d) ? lds[t - d] : 0;
        __syncthreads();
        lds[t] += tmp;
    }
    __syncthreads();
    int thrBase = base_s + lds[t] - s;
    int4 o;
    o.x = thrBase;
    o.y = thrBase + v.x;
    o.z = thrBase + v.x + v.y;
    o.w = thrBase + v.x + v.y + v.z;
    if (base + 3 < n) *(int4*)(cnt + base) = o;
    else {
        if (base + 0 < n) cnt[base + 0] = o.x;
        if (base + 1 < n) cnt[base + 1] = o.y;
        if (base + 2 < n) cnt[base + 2] = o.z;
        if (base + 3 < n) cnt[base + 3] = o.w;
    }
}

// bin edges into CSR order as packed 8B records (col, attr*(1-ALPHA))
__global__ void k_build(const int* __restrict__ ei, const float* __restrict__ attr,
                        int* __restrict__ cur, float2* __restrict__ recs, int E) {
    int e = blockIdx.x * 256 + threadIdx.x;
    if (e >= E) return;
    int row = ei[e];
    int pos = atomicAdd(&cur[row], 1);
    recs[pos] = make_float2(__int_as_float(ei[E + e]), (1.0f - ALPHA) * attr[e]);
}

__device__ inline void fma8(float* acc, float a, uint4 v) {
    acc[0] += a * __uint_as_float(v.x << 16);
    acc[1] += a * __uint_as_float(v.x & 0xffff0000u);
    acc[2] += a * __uint_as_float(v.y << 16);
    acc[3] += a * __uint_as_float(v.y & 0xffff0000u);
    acc[4] += a * __uint_as_float(v.z << 16);
    acc[5] += a * __uint_as_float(v.z & 0xffff0000u);
    acc[6] += a * __uint_as_float(v.w << 16);
    acc[7] += a * __uint_as_float(v.w & 0xffff0000u);
}

// FUSED, 16 rows/block. Gather: 16-lane group per row (lane = 8 channels,
// one uint4 bf16 load per edge), 4-way edge unroll -> 4 independent chains
// per wave. LDS: hs[row][128 bf16], 16B-granule swizzle gi ^= (row&7) ->
// ds_write_b128 / ds_read_b128 both <=2-way (free). GEMM: wave wv does
// n-tiles {2wv,2wv+1}: 8 mfma_16x16x32_bf16 vs L1-resident Wt; fp32 out once.
template <int USE_BF16>
__global__ __launch_bounds__(256)
void k_fused16(const void* __restrict__ xsrc, const int* __restrict__ cnt,
               const float2* __restrict__ recs, const float4* __restrict__ init4,
               const ushort* __restrict__ Wt, float* __restrict__ out, int N) {
    __shared__ ushort hs[16 * C_DIM];          // 4 KB swizzled bf16 tile
    const int tid = threadIdx.x;
    const long R0 = (long)blockIdx.x * 16;

    // ---------------- gather phase ----------------
    {
        const int g = tid >> 4;                // row group 0..15
        const int l = tid & 15;                // channel lane: ch l*8..l*8+7
        long r = R0 + g;
        float acc[8] = {0.f, 0.f, 0.f, 0.f, 0.f, 0.f, 0.f, 0.f};
        if (r < N) {
            int start = (r == 0) ? 0 : cnt[r - 1];
            int end = cnt[r];
            int k = start;
            if (USE_BF16) {
                const uint4* xb4 = (const uint4*)xsrc;   // x row = 16 uint4
                for (; k + 4 <= end; k += 4) {
                    float2 e0 = recs[k + 0];
                    float2 e1 = recs[k + 1];
                    float2 e2 = recs[k + 2];
                    float2 e3 = recs[k + 3];
                    uint4 v0 = xb4[(size_t)__float_as_int(e0.x) * 16 + l];
                    uint4 v1 = xb4[(size_t)__float_as_int(e1.x) * 16 + l];
                    uint4 v2 = xb4[(size_t)__float_as_int(e2.x) * 16 + l];
                    uint4 v3 = xb4[(size_t)__float_as_int(e3.x) * 16 + l];
                    fma8(acc, e0.y, v0);
                    fma8(acc, e1.y, v1);
                    fma8(acc, e2.y, v2);
                    fma8(acc, e3.y, v3);
                }
                if (k + 2 <= end) {
                    float2 e0 = recs[k + 0];
                    float2 e1 = recs[k + 1];
                    uint4 v0 = xb4[(size_t)__float_as_int(e0.x) * 16 + l];
                    uint4 v1 = xb4[(size_t)__float_as_int(e1.x) * 16 + l];
                    fma8(acc, e0.y, v0);
                    fma8(acc, e1.y, v1);
                    k += 2;
                }
                if (k < end) {
                    float2 e0 = recs[k];
                    uint4 v0 = xb4[(size_t)__float_as_int(e0.x) * 16 + l];
                    fma8(acc, e0.y, v0);
                }
            } else {
                const float4* x4 = (const float4*)xsrc;
                for (; k < end; ++k) {
                    float2 e0 = recs[k];
                    const float4* xr = x4 + (size_t)__float_as_int(e0.x) * 32 + l * 2;
                    float4 a0 = xr[0], a1 = xr[1];
                    float w = e0.y;
                    acc[0] += w * a0.x; acc[1] += w * a0.y;
                    acc[2] += w * a0.z; acc[3] += w * a0.w;
                    acc[4] += w * a1.x; acc[5] += w * a1.y;
                    acc[6] += w * a1.z; acc[7] += w * a1.w;
                }
            }
            float4 i0 = init4[r * 32 + l * 2];
            float4 i1 = init4[r * 32 + l * 2 + 1];
            acc[0] += ALPHA * i0.x; acc[1] += ALPHA * i0.y;
            acc[2] += ALPHA * i0.z; acc[3] += ALPHA * i0.w;
            acc[4] += ALPHA * i1.x; acc[5] += ALPHA * i1.y;
            acc[6] += ALPHA * i1.z; acc[7] += ALPHA * i1.w;
        }
        uint4 o;
        o.x = pack2(acc[0], acc[1]);
        o.y = pack2(acc[2], acc[3]);
        o.z = pack2(acc[4], acc[5]);
        o.w = pack2(acc[6], acc[7]);
        int gi = l ^ (g & 7);                  // 16B-granule swizzle
        *(uint4*)&hs[g * 128 + gi * 8] = o;
    }
    __syncthreads();

    // ---------------- GEMM phase ----------------
    {
        const int lane = tid & 63;
        const int wv = tid >> 6;               // n-tile pair {2wv, 2wv+1}
        const int m = lane & 15, gg = lane >> 4;
        const uint4* W16 = (const uint4*)Wt;   // Wt[n][k]: 16 uint4 per row

        f32x4 acc[2];
        acc[0] = (f32x4){0.f, 0.f, 0.f, 0.f};
        acc[1] = (f32x4){0.f, 0.f, 0.f, 0.f};

#pragma unroll
        for (int ks = 0; ks < 4; ++ks) {
            int gi = (ks * 4 + gg) ^ (m & 7);  // A: lane holds A[m][ks*32+gg*8 ..+7]
            short8v a = *(const short8v*)&hs[m * 128 + gi * 8];
#pragma unroll
            for (int j = 0; j < 2; ++j) {
                int nt = wv * 2 + j;
                union { uint4 q; short8v v; } b;   // B: Wt[nt*16+m][ks*32+gg*8 ..+7]
                b.q = W16[(nt * 16 + m) * 16 + (ks * 4 + gg)];
                acc[j] = __builtin_amdgcn_mfma_f32_16x16x32_bf16(a, b.v, acc[j], 0, 0, 0);
            }
        }

        // C/D layout: col = lane&15, row = (lane>>4)*4 + reg
#pragma unroll
        for (int j = 0; j < 2; ++j) {
            int nt = wv * 2 + j;
            long rb = R0 + gg * 4;
#pragma unroll
            for (int reg = 0; reg < 4; ++reg) {
                long r = rb + reg;
                if (r >= N) continue;
                out[r * C_DIM + nt * 16 + m] = acc[j][reg];
            }
        }
    }
}

extern "C" void kernel_launch(void* const* d_in, const int* in_sizes, int n_in,
                              void* d_out, int out_size, void* d_ws, size_t ws_size,
                              hipStream_t stream) {
    const float* x      = (const float*)d_in[0];
    const int*   ei     = (const int*)d_in[1];
    const float* attr   = (const float*)d_in[2];
    const float* init_x = (const float*)d_in[3];
    const float* W      = (const float*)d_in[4];
    float* out = (float*)d_out;

    const int N = in_sizes[0] / C_DIM;
    const int E = in_sizes[2];

    const int N_pad = (N + 255) & ~255;
    const size_t cnt_bytes = (size_t)N_pad * 4;
    const size_t rec_bytes = (size_t)E * 8;
    const size_t wt_bytes  = (size_t)C_DIM * C_DIM * 2;   // 32 KB
    const size_t xb_bytes  = (size_t)N * C_DIM * 2;       // bf16 copy of x
    const size_t base_need = cnt_bytes + 1024 + rec_bytes + wt_bytes;
    const bool use_bf16 = ws_size >= base_need + xb_bytes;

    char* wsp = (char*)d_ws;
    int*    cnt      = (int*)wsp;
    int*    partials = cnt + N_pad;
    float2* recs     = (float2*)((char*)partials + 1024);
    ushort* Wt       = (ushort*)((char*)recs + rec_bytes);
    uint4*  xb       = use_bf16 ? (uint4*)((char*)Wt + wt_bytes) : nullptr;

    const int B = (N + 1023) / 1024;   // scan blocks (98 for N=100000), must be <=256
    const int n8 = use_bf16 ? (N * C_DIM / 8) : 0;
    int prep_elems = (n8 > N) ? n8 : N;
    if (prep_elems < C_DIM * C_DIM) prep_elems = C_DIM * C_DIM;

    k_prep<<<(prep_elems + 255) / 256, 256, 0, stream>>>((const float4*)x, xb, n8,
                                                         cnt, N, W, Wt);
    k_hist<<<(E + 255) / 256, 256, 0, stream>>>(ei, cnt, E);
    k_blockreduce<<<B, 256, 0, stream>>>(cnt, partials, N);
    k_blockscan<<<B, 256, 0, stream>>>(cnt, partials, N);
    k_build<<<(E + 255) / 256, 256, 0, stream>>>(ei, attr, cnt, recs, E);
    if (use_bf16) {
        k_fused16<1><<<(N + 15) / 16, 256, 0, stream>>>((const void*)xb, cnt, recs,
                                                        (const float4*)init_x, Wt, out, N);
    } else {
        k_fused16<0><<<(N + 15) / 16, 256, 0, stream>>>((const void*)x, cnt, recs,
                                                        (const float4*)init_x, Wt, out, N);
    }
}